// Round 5
// baseline (168.367 us; speedup 1.0000x reference)
//
#include <hip/hip_runtime.h>

#define T_LEN 50
#define I_IN 2
#define HID 4

typedef _Float16 hf2 __attribute__((ext_vector_type(2)));

__device__ __forceinline__ float EXP2(float x){
#if __has_builtin(__builtin_amdgcn_exp2f)
    return __builtin_amdgcn_exp2f(x);
#else
    return exp2f(x);
#endif
}
__device__ __forceinline__ float RCP(float x){
#if __has_builtin(__builtin_amdgcn_rcpf)
    return __builtin_amdgcn_rcpf(x);
#else
    return 1.0f/x;
#endif
}
__device__ __forceinline__ hf2 PK(float a, float b){
#if __has_builtin(__builtin_amdgcn_cvt_pkrtz)
    return __builtin_bit_cast(hf2, __builtin_amdgcn_cvt_pkrtz(a, b));
#else
    hf2 r; r.x = (_Float16)a; r.y = (_Float16)b; return r;
#endif
}
__device__ __forceinline__ float DOT2(hf2 a, hf2 b, float c){
#if __has_builtin(__builtin_amdgcn_fdot2)
    return __builtin_amdgcn_fdot2(a, b, c, false);
#else
    return c + (float)a.x*(float)b.x + (float)a.y*(float)b.y;
#endif
}

// quad_perm DPP move on raw bits. Broadcast lane K of quad: CTRL=K*0x55.
template<int CTRL>
__device__ __forceinline__ int qdpp_i(int v){
#if __has_builtin(__builtin_amdgcn_mov_dpp)
    return __builtin_amdgcn_mov_dpp(v, CTRL, 0xF, 0xF, true);
#else
    int lane = threadIdx.x & 63;
    int sel = (CTRL >> (2*(lane & 3))) & 3;
    return __shfl(v, (lane & ~3) + sel, 64);
#endif
}
template<int CTRL>
__device__ __forceinline__ float qdpp(float v){
    return __int_as_float(qdpp_i<CTRL>(__float_as_int(v)));
}
template<int CTRL>
__device__ __forceinline__ hf2 qdpp_h(hf2 v){
    return __builtin_bit_cast(hf2, qdpp_i<CTRL>(__builtin_bit_cast(int, v)));
}

// broadcast+pack: from per-lane h (unit j in lane j of quad) build (h0,h1),(h2,h3)
__device__ __forceinline__ void bpack(float h, hf2& lo, hf2& hi){
    const float hs = qdpp<0xB1>(h);       // neighbor's h
    const hf2 hh = PK(h, hs);             // lane0:(h0,h1) lane2:(h2,h3)
    lo = qdpp_h<0x00>(hh);
    hi = qdpp_h<0xAA>(hh);
}

// LUT: T(y) = tanh(y), y in [-8,8], 2048 intervals (1/128 each).
// Table coordinate t = 128*y + 1024. Entry: (value, next-value).
// Gates arrive ALREADY in table coords (scale folded into weights/bias).
#define TBL_N 2048
__device__ __forceinline__ float lut(const float2* __restrict__ tbl, float t){
    t = fminf(t, 2046.999f);
    t = fmaxf(t, 0.0f);
    const float fl = floorf(t);
    const float fr = t - fl;
    const float2 e = tbl[(int)fl];
    return fmaf(fr, e.y, e.x);
}

// act: gates g[] in table coords (i,f,o at 64x+1024; g at 128x+1024)
__device__ __forceinline__ void lstm_act_lut(const float2* __restrict__ tbl,
                                             const float g[4], float& c, float& h){
    const float Ti = lut(tbl, g[0]);
    const float Tf = lut(tbl, g[1]);
    const float Tg = lut(tbl, g[2]);
    const float To = lut(tbl, g[3]);
    const float si = fmaf(0.5f, Ti, 0.5f);
    const float sf = fmaf(0.5f, Tf, 0.5f);
    const float so = fmaf(0.5f, To, 0.5f);
    c = fmaf(sf, c, si*Tg);
    const float Tc = lut(tbl, fmaf(c, 128.0f, 1024.0f));
    h = so * Tc;
}

__global__ __launch_bounds__(256) void lstm_fused(
    const float* __restrict__ x,
    const float* __restrict__ Wih0, const float* __restrict__ Whh0,
    const float* __restrict__ bih0, const float* __restrict__ bhh0,
    const float* __restrict__ Wih1, const float* __restrict__ Whh1,
    const float* __restrict__ bih1, const float* __restrict__ bhh1,
    const float* __restrict__ Wout, const float* __restrict__ bout,
    float* __restrict__ out, int B)
{
    __shared__ float2 tbl[TBL_N];
    __shared__ float wout_s[T_LEN*HID];
    const int tid = threadIdx.x;

    // build tanh table (8 entries per thread, one-time)
    for (int k = tid; k < TBL_N; k += 256){
        const float y0 = -8.0f + (float)k * (1.0f/128.0f);
        const float v0 = tanhf(y0);
        const float v1 = tanhf(y0 + (1.0f/128.0f));
        tbl[k] = make_float2(v0, v1 - v0);
    }
    if (tid < T_LEN*HID) wout_s[tid] = Wout[tid];
    __syncthreads();

    const int gtid = blockIdx.x*256 + tid;
    const int e = gtid >> 2;      // batch element
    const int j = tid & 3;        // hidden unit owned by this lane
    if (e >= B) return;

    // Per-lane weights for unit j, pre-scaled into table coordinates:
    // sigma gates (i,f,o): arg y = g/2 -> t = 64*g + 1024
    // tanh gate (g):       t = 128*g + 1024
    float b0[4], b1[4];
    hf2 wx0p[4], wh0p[4][2], wx1p[4][2], wh1p[4][2];
#pragma unroll
    for (int G = 0; G < 4; ++G){
        const float s = (G == 2) ? 128.0f : 64.0f;
        const int r = G*4 + j;
        wx0p[G]    = PK(Wih0[r*2+0]*s, Wih0[r*2+1]*s);
        wh0p[G][0] = PK(Whh0[r*4+0]*s, Whh0[r*4+1]*s);
        wh0p[G][1] = PK(Whh0[r*4+2]*s, Whh0[r*4+3]*s);
        wx1p[G][0] = PK(Wih1[r*4+0]*s, Wih1[r*4+1]*s);
        wx1p[G][1] = PK(Wih1[r*4+2]*s, Wih1[r*4+3]*s);
        wh1p[G][0] = PK(Whh1[r*4+0]*s, Whh1[r*4+1]*s);
        wh1p[G][1] = PK(Whh1[r*4+2]*s, Whh1[r*4+3]*s);
        b0[G] = (bih0[r] + bhh0[r])*s + 1024.0f;
        b1[G] = (bih1[r] + bhh1[r])*s + 1024.0f;
    }

    float h0 = 0.f, c0 = 0.f, h1 = 0.f, c1 = 0.f, acc = 0.f;
    hf2 h0p[2] = { hf2{0,0}, hf2{0,0} };
    hf2 h1p[2] = { hf2{0,0}, hf2{0,0} };
    const float* xp = x + (size_t)e * (T_LEN*I_IN);

    auto step = [&](hf2 xpk, int t){
        // ---- layer 0 gates (results in table coords) ----
        float g[4];
#pragma unroll
        for (int G = 0; G < 4; ++G){
            float a = DOT2(wx0p[G], xpk, b0[G]);
            a = DOT2(wh0p[G][0], h0p[0], a);
            a = DOT2(wh0p[G][1], h0p[1], a);
            g[G] = a;
        }
        lstm_act_lut(tbl, g, c0, h0);
        bpack(h0, h0p[0], h0p[1]);

        // ---- layer 1 gates ----
#pragma unroll
        for (int G = 0; G < 4; ++G){
            float a = DOT2(wx1p[G][0], h0p[0], b1[G]);
            a = DOT2(wx1p[G][1], h0p[1], a);
            a = DOT2(wh1p[G][0], h1p[0], a);
            a = DOT2(wh1p[G][1], h1p[1], a);
            g[G] = a;
        }
        lstm_act_lut(tbl, g, c1, h1);
        bpack(h1, h1p[0], h1p[1]);

        acc = fmaf(h1, wout_s[t*4 + j], acc);
    };

#pragma unroll 2
    for (int tt = 0; tt < T_LEN/2; ++tt){
        const float4 xv = *reinterpret_cast<const float4*>(xp + tt*4);
        step(PK(xv.x, xv.y), 2*tt);
        step(PK(xv.z, xv.w), 2*tt + 1);
    }

    // quad reduction of acc: xor1 = quad_perm[1,0,3,2]=0xB1, xor2 = [2,3,0,1]=0x4E
    acc += qdpp<0xB1>(acc);
    acc += qdpp<0x4E>(acc);

    if (j == 0){
        const float z = acc + bout[0];
        out[e] = RCP(1.0f + EXP2(z * -1.4426950408889634f));   // sigmoid(z)
    }
}

extern "C" void kernel_launch(void* const* d_in, const int* in_sizes, int n_in,
                              void* d_out, int out_size, void* d_ws, size_t ws_size,
                              hipStream_t stream)
{
    const float* x    = (const float*)d_in[0];
    const float* Wih0 = (const float*)d_in[1];
    const float* Whh0 = (const float*)d_in[2];
    const float* bih0 = (const float*)d_in[3];
    const float* bhh0 = (const float*)d_in[4];
    const float* Wih1 = (const float*)d_in[5];
    const float* Whh1 = (const float*)d_in[6];
    const float* bih1 = (const float*)d_in[7];
    const float* bhh1 = (const float*)d_in[8];
    const float* Wout = (const float*)d_in[9];
    const float* bout = (const float*)d_in[10];
    float* out = (float*)d_out;

    const int B = in_sizes[0] / (T_LEN*I_IN);
    const int total = B * 4;
    const int threads = 256;
    const int blocks = (total + threads - 1) / threads;
    lstm_fused<<<blocks, threads, 0, stream>>>(x, Wih0, Whh0, bih0, bhh0,
                                               Wih1, Whh1, bih1, bhh1,
                                               Wout, bout, out, B);
}